// Round 1
// baseline (2984.283 us; speedup 1.0000x reference)
//
#include <hip/hip_runtime.h>

// BiLSTM: T=16384 tokens = 128 segs x 128, D=1024, H=512, bidirectional.
// Plan:
//  1) cast X -> bf16; pack W_ih_f|W_ih_b -> bf16 [4096][1024]; bias concat.
//  2) MFMA GEMM: XP[16384][4096] = X @ Wcat^T + bias  (bf16 inputs, fp32 acc, bf16 store)
//  3) 128x lstm_step (fp32 vector): per step, 256 blocks; block = (dir, 32-chain tile, 16-unit tile)
//  4) write boundaries as floats to d_out tail.

typedef __attribute__((ext_vector_type(8))) short bf16x8;
typedef __attribute__((ext_vector_type(4))) float f32x4;

__device__ __forceinline__ unsigned short f2bf(float f) {
  unsigned int x = __builtin_bit_cast(unsigned int, f);
  x += 0x7fffu + ((x >> 16) & 1u);
  return (unsigned short)(x >> 16);
}
__device__ __forceinline__ float bf2f(unsigned short u) {
  unsigned int x = ((unsigned int)u) << 16;
  return __builtin_bit_cast(float, x);
}
__device__ __forceinline__ float sigm(float x) { return 1.f / (1.f + __expf(-x)); }
__device__ __forceinline__ float tanhfast(float x) {
  float e = __expf(2.f * x);
  return 1.f - 2.f / (e + 1.f);
}

__device__ __forceinline__ void gl_lds16(const void* g, void* l) {
  __builtin_amdgcn_global_load_lds((const __attribute__((address_space(1))) unsigned int*)g,
                                   (__attribute__((address_space(3))) unsigned int*)l, 16, 0, 0);
}

// ---------------- cast X to bf16 ----------------
__global__ __launch_bounds__(256) void cast_x(const float* __restrict__ X,
                                              unsigned short* __restrict__ Xb) {
  const int i = blockIdx.x * 256 + threadIdx.x;  // float4 index, total 4194304
  const float4 v = ((const float4*)X)[i];
  uint2 o;
  o.x = (unsigned int)f2bf(v.x) | ((unsigned int)f2bf(v.y) << 16);
  o.y = (unsigned int)f2bf(v.z) | ((unsigned int)f2bf(v.w) << 16);
  ((uint2*)Xb)[i] = o;
}

// ---------------- pack W_ih (concat dirs) to bf16 + bias ----------------
__global__ __launch_bounds__(256) void pack_w(const float* __restrict__ Wif,
                                              const float* __restrict__ bf_,
                                              const float* __restrict__ Wib,
                                              const float* __restrict__ bb_,
                                              unsigned short* __restrict__ Wc,
                                              float* __restrict__ biasp) {
  const int pr = blockIdx.x;  // 0..4095
  const int d = pr >> 11, r = pr & 2047;
  const float* src = (d ? Wib : Wif) + (size_t)r * 1024;
  const int t = threadIdx.x;  // 256 threads x float4 = 1024 floats
  const float4 v = ((const float4*)src)[t];
  uint2 o;
  o.x = (unsigned int)f2bf(v.x) | ((unsigned int)f2bf(v.y) << 16);
  o.y = (unsigned int)f2bf(v.z) | ((unsigned int)f2bf(v.w) << 16);
  ((uint2*)(Wc + (size_t)pr * 1024))[t] = o;
  if (t == 0) biasp[pr] = (d ? bb_ : bf_)[r];
}

// ---------------- MFMA GEMM: XP = Xb @ Wc^T + bias ----------------
// A [16384][1024] bf16 row-major; B [4096][1024] bf16 row-major (= B^T layout);
// C [16384][4096] bf16. 128x128 tile, K-step 32, 4 waves (2x2 of 64x64).
__global__ __launch_bounds__(256) void gemm_xp(const unsigned short* __restrict__ A,
                                               const unsigned short* __restrict__ B,
                                               const float* __restrict__ bias,
                                               unsigned short* __restrict__ C) {
  __shared__ unsigned short As[128 * 32];
  __shared__ unsigned short Bs[128 * 32];
  const int tid = threadIdx.x;
  const int lane = tid & 63;
  const int wid = tid >> 6;
  const int wm = wid >> 1, wn = wid & 1;
  const long brow = (long)blockIdx.x * 128;
  const long bcol = (long)blockIdx.y * 128;

  f32x4 acc[4][4];
  const f32x4 z = {0.f, 0.f, 0.f, 0.f};
#pragma unroll
  for (int i = 0; i < 4; ++i)
#pragma unroll
    for (int j = 0; j < 4; ++j) acc[i][j] = z;

  const int r16a = wid * 2, r16b = wid * 2 + 1;
  const int srow = lane >> 2;
  const int scol = (lane & 3) * 8;
  const unsigned short* ga0 = A + (brow + r16a * 16 + srow) * 1024 + scol;
  const unsigned short* ga1 = A + (brow + r16b * 16 + srow) * 1024 + scol;
  const unsigned short* gb0 = B + (bcol + r16a * 16 + srow) * 1024 + scol;
  const unsigned short* gb1 = B + (bcol + r16b * 16 + srow) * 1024 + scol;
  unsigned short* la0 = &As[r16a * 512];
  unsigned short* la1 = &As[r16b * 512];
  unsigned short* lb0 = &Bs[r16a * 512];
  unsigned short* lb1 = &Bs[r16b * 512];

  for (int ks = 0; ks < 32; ++ks) {
    const int k0 = ks * 32;
    gl_lds16(ga0 + k0, la0);
    gl_lds16(ga1 + k0, la1);
    gl_lds16(gb0 + k0, lb0);
    gl_lds16(gb1 + k0, lb1);
    __syncthreads();  // drains vmcnt(0): LDS tiles ready
    bf16x8 av[4], bv[4];
#pragma unroll
    for (int f = 0; f < 4; ++f) {
      av[f] = *(const bf16x8*)&As[(wm * 64 + f * 16 + (lane & 15)) * 32 + (lane >> 4) * 8];
      bv[f] = *(const bf16x8*)&Bs[(wn * 64 + f * 16 + (lane & 15)) * 32 + (lane >> 4) * 8];
    }
#pragma unroll
    for (int fm = 0; fm < 4; ++fm)
#pragma unroll
      for (int fn = 0; fn < 4; ++fn)
        acc[fm][fn] = __builtin_amdgcn_mfma_f32_16x16x32_bf16(av[fm], bv[fn], acc[fm][fn], 0, 0, 0);
    __syncthreads();  // compute done before next stage overwrites
  }
  // epilogue: C/D layout col=lane&15, row=(lane>>4)*4+r  [guide-verified m89/m91]
  const int crow0 = wm * 64 + (lane >> 4) * 4;
  const int ccol0 = wn * 64 + (lane & 15);
#pragma unroll
  for (int fm = 0; fm < 4; ++fm) {
#pragma unroll
    for (int fn = 0; fn < 4; ++fn) {
      const long col = bcol + ccol0 + fn * 16;
      const float bsv = bias[col];
#pragma unroll
      for (int r = 0; r < 4; ++r) {
        const long row = brow + crow0 + fm * 16 + r;
        C[row * 4096 + col] = f2bf(acc[fm][fn][r] + bsv);
      }
    }
  }
}

// ---------------- one recurrence step (fp32) ----------------
// 256 blocks x 256 thr. Block = (dir, chain tile ct of 32, unit tile ut of 16 units).
// Thread: kh = tid>>7 (k-half), ug = (tid&127)>>3 (unit 0..15), cg = tid&7;
// computes 4 chains (cg, cg+8, cg+16, cg+24) x 4 gates over its 32-k slice of
// each 64-k chunk. h tile in LDS (padded), W chunk in LDS ([g*16+u][68] packing
// -> lanes hit distinct bank quads on reads).
__global__ __launch_bounds__(256) void lstm_step(
    const unsigned short* __restrict__ XPb, const float* __restrict__ Whf,
    const float* __restrict__ Whb, const float* __restrict__ h_prev,
    float* __restrict__ h_next, float* __restrict__ cst, float* __restrict__ out,
    const int tau) {
  __shared__ float h_s[32][516];
  __shared__ float W_s[64][68];
  __shared__ float part[128][16];
  const int tid = threadIdx.x;
  const int bid = blockIdx.x;
  const int dir = bid >> 7;
  const int rb = bid & 127;
  const int ct = rb >> 5;
  const int ut = rb & 31;
  const int kh = tid >> 7;
  const int tt = tid & 127;
  const int ug = tt >> 3;
  const int cg = tt & 7;

  const float* hp = h_prev + (dir * 128 + ct * 32) * 512;
#pragma unroll
  for (int j = 0; j < 16; ++j) {
    const int f4 = tid + j * 256;
    const int row = f4 >> 7;
    const int k4 = f4 & 127;
    *(float4*)(&h_s[row][k4 * 4]) = *(const float4*)(hp + row * 512 + k4 * 4);
  }

  float acc[4][4];
#pragma unroll
  for (int c = 0; c < 4; ++c)
#pragma unroll
    for (int g = 0; g < 4; ++g) acc[c][g] = 0.f;

  const float* Wh = dir ? Whb : Whf;
  const int klo = kh * 32;
  for (int kc = 0; kc < 8; ++kc) {
    const int k0 = kc * 64;
    __syncthreads();  // h_s ready (kc==0); prev W_s fully consumed (kc>0)
#pragma unroll
    for (int j = 0; j < 4; ++j) {
      const int f4 = tid + j * 256;
      const int rl = f4 >> 4;  // 0..63 = g*16+u
      const int k4 = f4 & 15;
      const int g = rl >> 4, u = rl & 15;
      *(float4*)(&W_s[rl][k4 * 4]) =
          *(const float4*)(Wh + (size_t)(g * 512 + ut * 16 + u) * 512 + k0 + k4 * 4);
    }
    __syncthreads();
#pragma unroll
    for (int q = 0; q < 8; ++q) {
      const int kk = klo + q * 4;
      const float4 w0 = *(const float4*)(&W_s[0 * 16 + ug][kk]);
      const float4 w1 = *(const float4*)(&W_s[1 * 16 + ug][kk]);
      const float4 w2 = *(const float4*)(&W_s[2 * 16 + ug][kk]);
      const float4 w3 = *(const float4*)(&W_s[3 * 16 + ug][kk]);
#pragma unroll
      for (int c = 0; c < 4; ++c) {
        const float4 hv = *(const float4*)(&h_s[cg + 8 * c][k0 + kk]);
        acc[c][0] += hv.x * w0.x + hv.y * w0.y + hv.z * w0.z + hv.w * w0.w;
        acc[c][1] += hv.x * w1.x + hv.y * w1.y + hv.z * w1.z + hv.w * w1.w;
        acc[c][2] += hv.x * w2.x + hv.y * w2.y + hv.z * w2.z + hv.w * w2.w;
        acc[c][3] += hv.x * w3.x + hv.y * w3.y + hv.z * w3.z + hv.w * w3.w;
      }
    }
  }
  __syncthreads();
  if (kh == 1) {
#pragma unroll
    for (int c = 0; c < 4; ++c)
#pragma unroll
      for (int g = 0; g < 4; ++g) part[tt][c * 4 + g] = acc[c][g];
  }
  __syncthreads();
  if (kh == 0) {
    const int unit = ut * 16 + ug;
    const int tcol = dir ? (127 - tau) : tau;
#pragma unroll
    for (int c = 0; c < 4; ++c) {
      const int seg = ct * 32 + cg + 8 * c;
      const long tok = (long)seg * 128 + tcol;
      const unsigned short* xp = XPb + tok * 4096 + dir * 2048 + unit;
      const float p0 = acc[c][0] + part[tt][c * 4 + 0] + bf2f(xp[0]);
      const float p1 = acc[c][1] + part[tt][c * 4 + 1] + bf2f(xp[512]);
      const float p2 = acc[c][2] + part[tt][c * 4 + 2] + bf2f(xp[1024]);
      const float p3 = acc[c][3] + part[tt][c * 4 + 3] + bf2f(xp[1536]);
      const float ig = sigm(p0), fg = sigm(p1), gg = tanhfast(p2), og = sigm(p3);
      const long sidx = (long)(dir * 128 + seg) * 512 + unit;
      float cv = cst[sidx];
      cv = fg * cv + ig * gg;
      cst[sidx] = cv;
      const float hv = og * tanhfast(cv);
      h_next[sidx] = hv;
      out[tok * 1024 + dir * 512 + unit] = hv;
    }
  }
}

// ---------------- boundaries passthrough ----------------
__global__ void wr_bounds(const int* __restrict__ b, float* __restrict__ o) {
  const int i = threadIdx.x;
  if (i < 129) o[i] = (float)b[i];
}

extern "C" void kernel_launch(void* const* d_in, const int* in_sizes, int n_in,
                              void* d_out, int out_size, void* d_ws, size_t ws_size,
                              hipStream_t stream) {
  const float* X = (const float*)d_in[0];
  const int* bnd = (const int*)d_in[1];
  const float* Wif = (const float*)d_in[2];
  const float* Whf = (const float*)d_in[3];
  const float* bf_ = (const float*)d_in[4];
  const float* Wib = (const float*)d_in[5];
  const float* Whb = (const float*)d_in[6];
  const float* bb_ = (const float*)d_in[7];
  float* out = (float*)d_out;

  // boundaries first (independent of workspace)
  wr_bounds<<<1, 256, 0, stream>>>(bnd, out + 16777216);

  char* ws = (char*)d_ws;
  const size_t NEED = 177750016ULL;
  if (ws_size < NEED) return;  // visible failure rather than OOB

  unsigned short* XPb = (unsigned short*)(ws + 0);           // 128 MB
  unsigned short* Xb = (unsigned short*)(ws + 134217728);    // 32 MB
  unsigned short* Wc = (unsigned short*)(ws + 167772160);    // 8 MB
  float* biasp = (float*)(ws + 176160768);                   // 16 KB
  float* hA = (float*)(ws + 176177152);                      // 512 KB
  float* hB = (float*)(ws + 176701440);                      // 512 KB
  float* cst = (float*)(ws + 177225728);                     // 512 KB

  cast_x<<<16384, 256, 0, stream>>>(X, Xb);
  pack_w<<<4096, 256, 0, stream>>>(Wif, bf_, Wib, bb_, Wc, biasp);
  dim3 gg(128, 32);
  gemm_xp<<<gg, 256, 0, stream>>>(Xb, Wc, biasp, XPb);

  hipMemsetAsync(hA, 0, 524288, stream);
  hipMemsetAsync(cst, 0, 524288, stream);

  for (int tau = 0; tau < 128; ++tau) {
    const float* hpv = (tau & 1) ? hB : hA;
    float* hn = (tau & 1) ? hA : hB;
    lstm_step<<<256, 256, 0, stream>>>(XPb, Whf, Whb, hpv, hn, cst, out, tau);
  }
}